// Round 2
// baseline (1755.156 us; speedup 1.0000x reference)
//
#include <hip/hip_runtime.h>
#include <math.h>

#define NB 512
#define NL 336
#define NC 321
#define NS 28
#define NW 12
#define NH 25
#define NP 8
#define NG 100  // 4*NH

__device__ __forceinline__ float sigm_f(float x) {
    return __fdividef(1.0f, 1.0f + __expf(-x));
}
__device__ __forceinline__ float tanh_f(float x) {
    float e = __expf(-2.0f * x);
    return __fdividef(1.0f - e, 1.0f + e);
}

// ---------------- Stage 1: mean + segment embedding ----------------
// x: (B, L, C). One block per b, threads over c (coalesced over c).
// seg_in[s,b,c] = sum_w (x[b,s*12+w,c] - mean[b,c]) * seg2d[c,w]
//              = rawdot - mean * sum_w seg2d[c,w]
extern "C" __global__ __launch_bounds__(384)
void k_seg(const float* __restrict__ x, const float* __restrict__ seg,
           float* __restrict__ seg_in, float* __restrict__ meanw) {
    const int b = blockIdx.x;
    const int c = threadIdx.x;
    if (c >= NC) return;
    float sw[NW];
#pragma unroll
    for (int w = 0; w < NW; ++w) sw[w] = seg[c * NW + w];
    float acc[NS];
    float sum = 0.0f;
    const float* xb = x + (size_t)b * NL * NC + c;
#pragma unroll 1
    for (int s = 0; s < NS; ++s) {
        float a = 0.0f;
#pragma unroll
        for (int w = 0; w < NW; ++w) {
            float v = xb[(s * NW + w) * NC];
            sum += v;
            a = fmaf(v, sw[w], a);
        }
        acc[s] = a;
    }
    float mean = sum * (1.0f / (float)NL);
    float ssum = 0.0f;
#pragma unroll
    for (int w = 0; w < NW; ++w) ssum += sw[w];
    meanw[b * NC + c] = mean;
#pragma unroll
    for (int s = 0; s < NS; ++s)
        seg_in[((size_t)s * NB + b) * NC + c] = acc[s] - mean * ssum;
}

// ---------------- Stage 2: per-channel LSTM encoder + decoder ----------------
// Block = (channel c, half of batch). 256 threads, each owns one (b,c) stream.
// Weights are block-uniform -> scalar loads; h/c state in registers.
extern "C" __global__ __launch_bounds__(256)
void k_lstm(const float* __restrict__ seg_in, const float* __restrict__ W_ih,
            const float* __restrict__ W_hh, const float* __restrict__ b_ih,
            const float* __restrict__ b_hh, const float* __restrict__ Wp,
            const float* __restrict__ bp, float* __restrict__ preds) {
    const int c = blockIdx.x;
    const int tid = threadIdx.x;
    const int b = blockIdx.y * 256 + tid;

    const float* __restrict__ wx  = W_ih + (size_t)c * NG;       // [g]
    const float* __restrict__ whh = W_hh + (size_t)c * NG * NH;  // [g*25+k]
    const float* __restrict__ bi  = b_ih + (size_t)c * NG;
    const float* __restrict__ bh  = b_hh + (size_t)c * NG;
    const float* __restrict__ wp  = Wp + (size_t)c * NH;
    const float bpc = bp[c];

    // Stage the 28 per-stream inputs in LDS so the time loop can stay rolled
    // (dynamic index) without spilling to scratch.
    __shared__ float lseg[NS * 256];
#pragma unroll
    for (int s = 0; s < NS; ++s)
        lseg[s * 256 + tid] = seg_in[((size_t)s * NB + b) * NC + c];

    float h[NH], cs[NH];
#pragma unroll
    for (int j = 0; j < NH; ++j) { h[j] = 0.0f; cs[j] = 0.0f; }

    float out = 0.0f;
#pragma unroll 1
    for (int t = 0; t < NS + NP - 1; ++t) {
        const float xt = (t < NS) ? lseg[t * 256 + tid] : out;
        float hn[NH];
#pragma unroll
        for (int j = 0; j < NH; ++j) {
            float ai = fmaf(xt, wx[j],          bi[j]          + bh[j]);
            float af = fmaf(xt, wx[NH + j],     bi[NH + j]     + bh[NH + j]);
            float ag = fmaf(xt, wx[2 * NH + j], bi[2 * NH + j] + bh[2 * NH + j]);
            float ao = fmaf(xt, wx[3 * NH + j], bi[3 * NH + j] + bh[3 * NH + j]);
#pragma unroll
            for (int k = 0; k < NH; ++k) {
                const float hk = h[k];
                ai = fmaf(hk, whh[(j) * NH + k], ai);
                af = fmaf(hk, whh[(NH + j) * NH + k], af);
                ag = fmaf(hk, whh[(2 * NH + j) * NH + k], ag);
                ao = fmaf(hk, whh[(3 * NH + j) * NH + k], ao);
            }
            const float cn = sigm_f(af) * cs[j] + sigm_f(ai) * tanh_f(ag);
            hn[j] = sigm_f(ao) * tanh_f(cn);
            cs[j] = cn;
        }
#pragma unroll
        for (int j = 0; j < NH; ++j) h[j] = hn[j];

        if (t >= NS - 1) {  // projection: out0 at t=27, then after each dec cell
            float o = bpc;
#pragma unroll
            for (int k = 0; k < NH; ++k) o = fmaf(h[k], wp[k], o);
            out = o;
            preds[((size_t)c * NP + (t - (NS - 1))) * NB + b] = o;
        }
    }
}

// ---------------- Stage 3: expand predictions to output ----------------
// out[b, p*12+w, c] = preds[b,c,p] * seg2d[c,w] + mean[b,c]
extern "C" __global__ __launch_bounds__(384)
void k_out(const float* __restrict__ preds, const float* __restrict__ seg,
           const float* __restrict__ meanw, float* __restrict__ out) {
    const int b = blockIdx.x;
    const int c = threadIdx.x;
    if (c >= NC) return;
    float sw[NW];
#pragma unroll
    for (int w = 0; w < NW; ++w) sw[w] = seg[c * NW + w];
    const float mean = meanw[b * NC + c];
    float pv[NP];
#pragma unroll
    for (int p = 0; p < NP; ++p) pv[p] = preds[((size_t)c * NP + p) * NB + b];
    float* ob = out + (size_t)b * (NP * NW) * NC + c;
#pragma unroll
    for (int p = 0; p < NP; ++p) {
#pragma unroll
        for (int w = 0; w < NW; ++w) {
            ob[(p * NW + w) * NC] = fmaf(pv[p], sw[w], mean);
        }
    }
}

extern "C" void kernel_launch(void* const* d_in, const int* in_sizes, int n_in,
                              void* d_out, int out_size, void* d_ws, size_t ws_size,
                              hipStream_t stream) {
    const float* x    = (const float*)d_in[0];
    const float* seg  = (const float*)d_in[1];
    const float* W_ih = (const float*)d_in[2];
    const float* W_hh = (const float*)d_in[3];
    const float* b_ih = (const float*)d_in[4];
    const float* b_hh = (const float*)d_in[5];
    const float* Wp   = (const float*)d_in[6];
    const float* bp   = (const float*)d_in[7];
    float* out = (float*)d_out;

    float* seg_in = (float*)d_ws;                   // 28*512*321 floats
    float* meanw  = seg_in + (size_t)NS * NB * NC;  // 512*321
    float* preds  = meanw + (size_t)NB * NC;        // 321*8*512

    k_seg<<<NB, 384, 0, stream>>>(x, seg, seg_in, meanw);
    k_lstm<<<dim3(NC, 2), 256, 0, stream>>>(seg_in, W_ih, W_hh, b_ih, b_hh, Wp, bp, preds);
    k_out<<<NB, 384, 0, stream>>>(preds, seg, meanw, out);
}

// Round 3
// 1099.853 us; speedup vs baseline: 1.5958x; 1.5958x over previous
//
#include <hip/hip_runtime.h>
#include <math.h>

#define NB 512
#define NL 336
#define NC 321
#define NS 28
#define NW 12
#define NH 25
#define NP 8
#define NG 100
#define NT (NS + NP - 1)  // 35 cell steps
#define BSL 32            // batch slab per block
#define NBT 2             // 16-wide batch tiles per slab
#define RST 40            // h-row stride in bf16 slots (padded for banks)

typedef __attribute__((ext_vector_type(8))) short bf16x8;
typedef __attribute__((ext_vector_type(4))) float f32x4;

union B8 { bf16x8 v; short s[8]; };

__device__ __forceinline__ short bhi_s(float x) {
    union { float f; unsigned u; } c; c.f = x; return (short)(c.u >> 16);
}
__device__ __forceinline__ float fhi_f(float x) {
    union { float f; unsigned u; } c; c.f = x; c.u &= 0xFFFF0000u; return c.f;
}
__device__ __forceinline__ short blo_s(float x) {
    return bhi_s(x - fhi_f(x));
}
__device__ __forceinline__ float sigm_f(float x) {
    return __fdividef(1.0f, 1.0f + __expf(-x));
}
__device__ __forceinline__ float tanh_f(float x) {
    float e = __expf(-2.0f * x);
    return __fdividef(1.0f - e, 1.0f + e);
}

// ---------------- Stage 1: mean + segment embedding (transposed out) --------
// x: (B, L, C). One block per b, threads over c (coalesced reads over c).
// seg_inT[s][c][b] = sum_w x[b,s*12+w,c]*seg2d[c,w] - mean[b,c]*sum_w seg2d
extern "C" __global__ __launch_bounds__(384)
void k_seg(const float* __restrict__ x, const float* __restrict__ seg,
           float* __restrict__ seg_inT, float* __restrict__ meanw) {
    const int b = blockIdx.x;
    const int c = threadIdx.x;
    if (c >= NC) return;
    float sw[NW];
#pragma unroll
    for (int w = 0; w < NW; ++w) sw[w] = seg[c * NW + w];
    float acc[NS];
    float sum = 0.0f;
    const float* xb = x + (size_t)b * NL * NC + c;
#pragma unroll 1
    for (int s = 0; s < NS; ++s) {
        float a = 0.0f;
#pragma unroll
        for (int w = 0; w < NW; ++w) {
            float v = xb[(s * NW + w) * NC];
            sum += v;
            a = fmaf(v, sw[w], a);
        }
        acc[s] = a;
    }
    const float mean = sum * (1.0f / (float)NL);
    float ssum = 0.0f;
#pragma unroll
    for (int w = 0; w < NW; ++w) ssum += sw[w];
    meanw[b * NC + c] = mean;
#pragma unroll
    for (int s = 0; s < NS; ++s)
        seg_inT[((size_t)s * NC + c) * NB + b] = acc[s] - mean * ssum;
}

// ---------------- Stage 2: MFMA LSTM ----------------------------------------
// One wave per (channel, 32-batch slab). gates^T = W'(112xK) @ h^T(Kx32) via
// mfma_f32_16x16x32_bf16, 3 K-tiles: Whi*hhi(+xt/bias tail), Wlo*hhi, Whi*hlo.
// Gate rows permuted G = mg*16 + q*4 + r <-> (gate=r, j=q*7+mg) so each lane's
// 4 C-regs are (i,f,g,o) of one hidden unit j -> lane-local activations.
extern "C" __global__ __launch_bounds__(64)
void k_lstm(const float* __restrict__ seg_inT, const float* __restrict__ W_ih,
            const float* __restrict__ W_hh, const float* __restrict__ b_ih,
            const float* __restrict__ b_hh, const float* __restrict__ Wp,
            const float* __restrict__ bp, float* __restrict__ preds) {
    const int c = blockIdx.x;
    const int b0 = blockIdx.y * BSL;
    const int tid = threadIdx.x;      // 0..63
    const int bb = tid & 15;          // within-tile row/col
    const int q  = tid >> 4;          // k-chunk / output row-quad

    __shared__ float wstage[NG * NH];
    __shared__ float bias_s[NG];
    __shared__ float wx_s[NG];
    __shared__ float wp_s[NH];
    __shared__ float seg_s[NS * BSL];
    __shared__ __align__(16) short hbuf_hi[BSL * RST];
    __shared__ __align__(16) short hbuf_lo[BSL * RST];

    // ---- stage weights / inputs ----
    for (int i = tid; i < NG * NH; i += 64) wstage[i] = W_hh[(size_t)c * NG * NH + i];
    for (int i = tid; i < NG; i += 64) {
        bias_s[i] = b_ih[(size_t)c * NG + i] + b_hh[(size_t)c * NG + i];
        wx_s[i]   = W_ih[(size_t)c * NG + i];
    }
    for (int i = tid; i < NH; i += 64) wp_s[i] = Wp[(size_t)c * NH + i];
    for (int i = tid; i < NS * BSL; i += 64) {
        const int s = i / BSL, bl = i % BSL;
        seg_s[i] = seg_inT[((size_t)s * NC + c) * NB + b0 + bl];
    }
    for (int i = tid; i < BSL * RST; i += 64) { hbuf_hi[i] = 0; hbuf_lo[i] = 0; }
    __syncthreads();

    // h-row slots: [0..24]=h, [25]=xh, [26]=xh, [27]=xl, [28]=1, [29]=1, [30,31]=0
    if (tid < BSL) {
        const int b = tid;
        hbuf_hi[b * RST + 28] = (short)0x3F80;
        hbuf_hi[b * RST + 29] = (short)0x3F80;
        const float xt = seg_s[0 * BSL + b];
        hbuf_hi[b * RST + 25] = bhi_s(xt);
        hbuf_hi[b * RST + 26] = bhi_s(xt);
        hbuf_hi[b * RST + 27] = blo_s(xt);
    }
    __syncthreads();

    // ---- build hoisted A-fragments (permuted weights) ----
    // A lane l: row G = mg*16 + (l&15), k = (l>>4)*8 + e
    const int qq = bb >> 2, rr = bb & 3;
    bf16x8 afr0[7], afr1[7], afr2[7];
#pragma unroll 1
    for (int mg = 0; mg < 7; ++mg) {
        const int jj = qq * 7 + mg;            // hidden index of this A-row
        const int grow = rr * NH + jj;         // original gate row (gate=rr)
        B8 f0, f1, f2;
#pragma unroll
        for (int e = 0; e < 8; ++e) {
            const int k = q * 8 + e;
            short v0 = 0, v1 = 0, v2 = 0;
            if (jj < NH) {
                if (k < NH) {
                    const float w = wstage[grow * NH + k];
                    v0 = bhi_s(w); v1 = blo_s(w); v2 = v0;
                } else if (k == 25) { v0 = bhi_s(wx_s[grow]); }
                else if (k == 26)   { v0 = blo_s(wx_s[grow]); }
                else if (k == 27)   { v0 = bhi_s(wx_s[grow]); }
                else if (k == 28)   { v0 = bhi_s(bias_s[grow]); }
                else if (k == 29)   { v0 = blo_s(bias_s[grow]); }
            }
            f0.s[e] = v0; f1.s[e] = v1; f2.s[e] = v2;
        }
        afr0[mg] = f0.v; afr1[mg] = f1.v; afr2[mg] = f2.v;
    }

    float wpl[7];
#pragma unroll
    for (int mg = 0; mg < 7; ++mg) {
        const int j = q * 7 + mg;
        wpl[mg] = (j < NH) ? wp_s[j] : 0.0f;
    }
    const float bpc = bp[c];

    float cst[NBT][7];
#pragma unroll
    for (int nb = 0; nb < NBT; ++nb)
#pragma unroll
        for (int mg = 0; mg < 7; ++mg) cst[nb][mg] = 0.0f;

    // ---- recurrence ----
#pragma unroll 1
    for (int t = 0; t < NT; ++t) {
        bf16x8 bh[NBT], bl[NBT];
#pragma unroll
        for (int nb = 0; nb < NBT; ++nb) {
            const int b = nb * 16 + bb;
            bh[nb] = *(const bf16x8*)&hbuf_hi[b * RST + q * 8];
            bl[nb] = *(const bf16x8*)&hbuf_lo[b * RST + q * 8];
        }
        const bool have_next = (t + 1 < NT);
#pragma unroll
        for (int nb = 0; nb < NBT; ++nb) {
            const int b = nb * 16 + bb;
            float pp = 0.0f;
#pragma unroll
            for (int mg = 0; mg < 7; ++mg) {
                f32x4 acc = {0.0f, 0.0f, 0.0f, 0.0f};
                acc = __builtin_amdgcn_mfma_f32_16x16x32_bf16(afr0[mg], bh[nb], acc, 0, 0, 0);
                acc = __builtin_amdgcn_mfma_f32_16x16x32_bf16(afr1[mg], bh[nb], acc, 0, 0, 0);
                acc = __builtin_amdgcn_mfma_f32_16x16x32_bf16(afr2[mg], bl[nb], acc, 0, 0, 0);
                // reg r: 0=i, 1=f, 2=g, 3=o for hidden j = q*7+mg of batch b
                const float cn = sigm_f(acc[1]) * cst[nb][mg] + sigm_f(acc[0]) * tanh_f(acc[2]);
                const float hn = sigm_f(acc[3]) * tanh_f(cn);
                cst[nb][mg] = cn;
                pp = fmaf(hn, wpl[mg], pp);
                const int j = q * 7 + mg;
                if (j < NH) {
                    hbuf_hi[b * RST + j] = bhi_s(hn);
                    hbuf_lo[b * RST + j] = blo_s(hn);
                }
            }
            float xt_next = 0.0f;
            if (t >= NS - 1) {
                pp += __shfl_xor(pp, 16);
                pp += __shfl_xor(pp, 32);
                const float ov = pp + bpc;
                if (q == 0) preds[((size_t)c * NP + (t - (NS - 1))) * NB + b0 + b] = ov;
                xt_next = ov;
            }
            if (have_next && (t + 1) < NS) xt_next = seg_s[(t + 1) * BSL + b];
            if (q == 0 && have_next) {
                hbuf_hi[b * RST + 25] = bhi_s(xt_next);
                hbuf_hi[b * RST + 26] = bhi_s(xt_next);
                hbuf_hi[b * RST + 27] = blo_s(xt_next);
            }
        }
    }
}

// ---------------- Stage 3: expand predictions to output ---------------------
extern "C" __global__ __launch_bounds__(384)
void k_out(const float* __restrict__ preds, const float* __restrict__ seg,
           const float* __restrict__ meanw, float* __restrict__ out) {
    const int b = blockIdx.x;
    const int c = threadIdx.x;
    if (c >= NC) return;
    float sw[NW];
#pragma unroll
    for (int w = 0; w < NW; ++w) sw[w] = seg[c * NW + w];
    const float mean = meanw[b * NC + c];
    float pv[NP];
#pragma unroll
    for (int p = 0; p < NP; ++p) pv[p] = preds[((size_t)c * NP + p) * NB + b];
    float* ob = out + (size_t)b * (NP * NW) * NC + c;
#pragma unroll
    for (int p = 0; p < NP; ++p) {
#pragma unroll
        for (int w = 0; w < NW; ++w) {
            ob[(p * NW + w) * NC] = fmaf(pv[p], sw[w], mean);
        }
    }
}

extern "C" void kernel_launch(void* const* d_in, const int* in_sizes, int n_in,
                              void* d_out, int out_size, void* d_ws, size_t ws_size,
                              hipStream_t stream) {
    const float* x    = (const float*)d_in[0];
    const float* seg  = (const float*)d_in[1];
    const float* W_ih = (const float*)d_in[2];
    const float* W_hh = (const float*)d_in[3];
    const float* b_ih = (const float*)d_in[4];
    const float* b_hh = (const float*)d_in[5];
    const float* Wp   = (const float*)d_in[6];
    const float* bp   = (const float*)d_in[7];
    float* out = (float*)d_out;

    float* seg_inT = (float*)d_ws;                     // 28*321*512
    float* meanw   = seg_inT + (size_t)NS * NC * NB;   // 512*321
    float* preds   = meanw + (size_t)NB * NC;          // 321*8*512

    k_seg<<<NB, 384, 0, stream>>>(x, seg, seg_inT, meanw);
    k_lstm<<<dim3(NC, NB / BSL), 64, 0, stream>>>(seg_inT, W_ih, W_hh, b_ih, b_hh, Wp, bp, preds);
    k_out<<<NB, 384, 0, stream>>>(preds, seg, meanw, out);
}

// Round 4
// 539.929 us; speedup vs baseline: 3.2507x; 2.0370x over previous
//
#include <hip/hip_runtime.h>
#include <math.h>

#define NB 512
#define NL 336
#define NC 321
#define NS 28
#define NW 12
#define NH 25
#define NP 8
#define NG 100
#define NT (NS + NP - 1)  // 35 cell steps
#define BSL 32            // batch slab per wave
#define NBT 2             // 16-wide batch tiles per slab
#define RST 40            // h-row stride in bf16 slots
#define WPB 4             // waves per block

typedef __attribute__((ext_vector_type(8))) short bf16x8;
typedef __attribute__((ext_vector_type(4))) float f32x4;

union B8 { bf16x8 v; short s[8]; };

__device__ __forceinline__ short bhi_s(float x) {
    union { float f; unsigned u; } c; c.f = x; return (short)(c.u >> 16);
}
__device__ __forceinline__ float fhi_f(float x) {
    union { float f; unsigned u; } c; c.f = x; c.u &= 0xFFFF0000u; return c.f;
}
__device__ __forceinline__ short blo_s(float x) {
    return bhi_s(x - fhi_f(x));
}
// sigma(a) * tanh(b) with 2 exp + 1 rcp
__device__ __forceinline__ float sigtanh(float a, float b) {
    float ea = __expf(-a);
    float eb = __expf(-2.0f * b);
    return __fdividef(1.0f - eb, (1.0f + ea) * (1.0f + eb));
}
__device__ __forceinline__ float sigm_f(float x) {
    return __fdividef(1.0f, 1.0f + __expf(-x));
}

// ---------------- Stage 1: mean + segment embedding (transposed out) --------
extern "C" __global__ __launch_bounds__(384)
void k_seg(const float* __restrict__ x, const float* __restrict__ seg,
           float* __restrict__ seg_inT, float* __restrict__ meanw) {
    const int b = blockIdx.x;
    const int c = threadIdx.x;
    if (c >= NC) return;
    float sw[NW];
#pragma unroll
    for (int w = 0; w < NW; ++w) sw[w] = seg[c * NW + w];
    float acc[NS];
    float sum = 0.0f;
    const float* xb = x + (size_t)b * NL * NC + c;
#pragma unroll 1
    for (int s = 0; s < NS; ++s) {
        float a = 0.0f;
#pragma unroll
        for (int w = 0; w < NW; ++w) {
            float v = xb[(s * NW + w) * NC];
            sum += v;
            a = fmaf(v, sw[w], a);
        }
        acc[s] = a;
    }
    const float mean = sum * (1.0f / (float)NL);
    float ssum = 0.0f;
#pragma unroll
    for (int w = 0; w < NW; ++w) ssum += sw[w];
    meanw[b * NC + c] = mean;
#pragma unroll
    for (int s = 0; s < NS; ++s)
        seg_inT[((size_t)s * NC + c) * NB + b] = acc[s] - mean * ssum;
}

// ---------------- Stage 2: MFMA LSTM ----------------------------------------
// 4 independent waves/block, each owns a (channel, 32-batch slab). No barriers.
// gates^T = W'(112xK) @ h^T(Kx32) via mfma_f32_16x16x32_bf16, 3 K-tiles:
// Whi*hhi(+xt/bias tail), Wlo*hhi, Whi*hlo (afr0 reused: lo-buf tail slots = 0).
// Gate rows permuted so each lane's 4 C-regs are (i,f,g,o) of one hidden j.
extern "C" __global__ __launch_bounds__(256, 4)
void k_lstm(const float* __restrict__ seg_inT, const float* __restrict__ W_ih,
            const float* __restrict__ W_hh, const float* __restrict__ b_ih,
            const float* __restrict__ b_hh, const float* __restrict__ Wp,
            const float* __restrict__ bp, float* __restrict__ preds) {
    const int c = blockIdx.x;
    const int wv = threadIdx.x >> 6;
    const int lane = threadIdx.x & 63;
    const int b0 = (blockIdx.y * WPB + wv) * BSL;
    const int bb = lane & 15;         // batch within 16-tile (B col)
    const int q  = lane >> 4;         // k-chunk / output row-quad

    __shared__ float seg_sm[WPB][NS * BSL];
    __shared__ __align__(16) short hbuf_hi[WPB][BSL * RST];
    __shared__ __align__(16) short hbuf_lo[WPB][BSL * RST];
    float* __restrict__ segw = seg_sm[wv];
    short* __restrict__ hh = hbuf_hi[wv];
    short* __restrict__ hl = hbuf_lo[wv];

    // ---- stage per-wave inputs; zero h buffers (wave-private -> no barrier) ----
    for (int i = lane; i < NS * BSL; i += 64) {
        const int s = i >> 5, bl = i & 31;
        segw[i] = seg_inT[((size_t)s * NC + c) * NB + b0 + bl];
    }
    for (int i = lane; i < BSL * RST; i += 64) { hh[i] = 0; hl[i] = 0; }

    // h-row slots: [0..24]=h, [25]=xh, [26]=xh, [27]=xl, [28]=1, [29]=1
    if (lane < BSL) {
        const int b = lane;
        hh[b * RST + 28] = (short)0x3F80;
        hh[b * RST + 29] = (short)0x3F80;
        const float xt = segw[0 * BSL + b];
        hh[b * RST + 25] = bhi_s(xt);
        hh[b * RST + 26] = bhi_s(xt);
        hh[b * RST + 27] = blo_s(xt);
    }

    // ---- build hoisted A-fragments straight from global (one-time, L2) ----
    // A lane l: row = (l&15) <-> (gate=row&3, j=(row>>2)*7+mg), k = (l>>4)*8+e
    const int qq = bb >> 2, rr = bb & 3;
    const float* __restrict__ whh = W_hh + (size_t)c * NG * NH;
    const float* __restrict__ wxp = W_ih + (size_t)c * NG;
    const float* __restrict__ bip = b_ih + (size_t)c * NG;
    const float* __restrict__ bhp = b_hh + (size_t)c * NG;
    bf16x8 afr0[7], afr1[7];
#pragma unroll 1
    for (int mg = 0; mg < 7; ++mg) {
        const int jj = qq * 7 + mg;
        const int grow = rr * NH + jj;
        B8 f0, f1;
#pragma unroll
        for (int e = 0; e < 8; ++e) {
            const int k = q * 8 + e;
            short v0 = 0, v1 = 0;
            if (jj < NH) {
                if (k < NH) {
                    const float w = whh[grow * NH + k];
                    v0 = bhi_s(w); v1 = blo_s(w);
                } else if (k == 25) { v0 = bhi_s(wxp[grow]); }
                else if (k == 26)   { v0 = blo_s(wxp[grow]); }
                else if (k == 27)   { v0 = bhi_s(wxp[grow]); }
                else if (k == 28)   { v0 = bhi_s(bip[grow] + bhp[grow]); }
                else if (k == 29)   { v0 = blo_s(bip[grow] + bhp[grow]); }
            }
            f0.s[e] = v0; f1.s[e] = v1;
        }
        afr0[mg] = f0.v; afr1[mg] = f1.v;
    }

    float wpl[7];
#pragma unroll
    for (int mg = 0; mg < 7; ++mg) {
        const int j = q * 7 + mg;
        wpl[mg] = (j < NH) ? Wp[(size_t)c * NH + j] : 0.0f;
    }
    const float bpc = bp[c];

    float cst[NBT][7];
#pragma unroll
    for (int nb = 0; nb < NBT; ++nb)
#pragma unroll
        for (int mg = 0; mg < 7; ++mg) cst[nb][mg] = 0.0f;

    // ---- recurrence ----
#pragma unroll 1
    for (int t = 0; t < NT; ++t) {
        bf16x8 bh[NBT], bl[NBT];
#pragma unroll
        for (int nb = 0; nb < NBT; ++nb) {
            const int b = nb * 16 + bb;
            bh[nb] = *(const bf16x8*)&hh[b * RST + q * 8];
            bl[nb] = *(const bf16x8*)&hl[b * RST + q * 8];
        }
        const bool have_next = (t + 1 < NT);
        const bool do_proj = (t >= NS - 1);
#pragma unroll
        for (int nb = 0; nb < NBT; ++nb) {
            const int b = nb * 16 + bb;
            float pp = 0.0f;
#pragma unroll
            for (int mg = 0; mg < 7; ++mg) {
                f32x4 acc = {0.0f, 0.0f, 0.0f, 0.0f};
                acc = __builtin_amdgcn_mfma_f32_16x16x32_bf16(afr0[mg], bh[nb], acc, 0, 0, 0);
                acc = __builtin_amdgcn_mfma_f32_16x16x32_bf16(afr1[mg], bh[nb], acc, 0, 0, 0);
                acc = __builtin_amdgcn_mfma_f32_16x16x32_bf16(afr0[mg], bl[nb], acc, 0, 0, 0);
                // regs: 0=i, 1=f, 2=g, 3=o for hidden j=q*7+mg, batch b
                const float cn = fmaf(sigm_f(acc[1]), cst[nb][mg], sigtanh(acc[0], acc[2]));
                const float hn = sigtanh(acc[3], cn);
                cst[nb][mg] = cn;
                if (do_proj) pp = fmaf(hn, wpl[mg], pp);
                const int j = q * 7 + mg;
                if (j < NH) {
                    hh[b * RST + j] = bhi_s(hn);
                    hl[b * RST + j] = blo_s(hn);
                }
            }
            float xt_next = 0.0f;
            if (do_proj) {
                pp += __shfl_xor(pp, 16);
                pp += __shfl_xor(pp, 32);
                const float ov = pp + bpc;
                if (q == 0) preds[((size_t)c * NP + (t - (NS - 1))) * NB + b0 + b] = ov;
                xt_next = ov;
            }
            if (have_next && (t + 1) < NS) xt_next = segw[(t + 1) * BSL + b];
            if (q == 0 && have_next) {
                hh[b * RST + 25] = bhi_s(xt_next);
                hh[b * RST + 26] = bhi_s(xt_next);
                hh[b * RST + 27] = blo_s(xt_next);
            }
        }
    }
}

// ---------------- Stage 3: expand predictions to output ---------------------
extern "C" __global__ __launch_bounds__(384)
void k_out(const float* __restrict__ preds, const float* __restrict__ seg,
           const float* __restrict__ meanw, float* __restrict__ out) {
    const int b = blockIdx.x;
    const int c = threadIdx.x;
    if (c >= NC) return;
    float sw[NW];
#pragma unroll
    for (int w = 0; w < NW; ++w) sw[w] = seg[c * NW + w];
    const float mean = meanw[b * NC + c];
    float pv[NP];
#pragma unroll
    for (int p = 0; p < NP; ++p) pv[p] = preds[((size_t)c * NP + p) * NB + b];
    float* ob = out + (size_t)b * (NP * NW) * NC + c;
#pragma unroll
    for (int p = 0; p < NP; ++p) {
#pragma unroll
        for (int w = 0; w < NW; ++w) {
            ob[(p * NW + w) * NC] = fmaf(pv[p], sw[w], mean);
        }
    }
}

extern "C" void kernel_launch(void* const* d_in, const int* in_sizes, int n_in,
                              void* d_out, int out_size, void* d_ws, size_t ws_size,
                              hipStream_t stream) {
    const float* x    = (const float*)d_in[0];
    const float* seg  = (const float*)d_in[1];
    const float* W_ih = (const float*)d_in[2];
    const float* W_hh = (const float*)d_in[3];
    const float* b_ih = (const float*)d_in[4];
    const float* b_hh = (const float*)d_in[5];
    const float* Wp   = (const float*)d_in[6];
    const float* bp   = (const float*)d_in[7];
    float* out = (float*)d_out;

    float* seg_inT = (float*)d_ws;                     // 28*321*512
    float* meanw   = seg_inT + (size_t)NS * NC * NB;   // 512*321
    float* preds   = meanw + (size_t)NB * NC;          // 321*8*512

    k_seg<<<NB, 384, 0, stream>>>(x, seg, seg_inT, meanw);
    k_lstm<<<dim3(NC, NB / (BSL * WPB)), 256, 0, stream>>>(seg_inT, W_ih, W_hh, b_ih, b_hh, Wp, bp, preds);
    k_out<<<NB, 384, 0, stream>>>(preds, seg, meanw, out);
}

// Round 5
// 536.895 us; speedup vs baseline: 3.2691x; 1.0057x over previous
//
#include <hip/hip_runtime.h>
#include <math.h>

#define NB 512
#define NL 336
#define NC 321
#define NS 28
#define NW 12
#define NH 25
#define NP 8
#define NG 100
#define NT (NS + NP - 1)  // 35 cell steps
#define BSL 32            // batch slab per wave
#define NBT 2             // 16-wide batch tiles per slab
#define RSTF 28           // h-row stride in f32 slots (2-way bank alias only)
#define WPB 4             // waves per block

typedef __attribute__((ext_vector_type(8))) short bf16x8;
typedef __attribute__((ext_vector_type(4))) float f32x4;

union B8 { bf16x8 v; short s[8]; };
union BU { bf16x8 v; unsigned u[4]; };

__device__ __forceinline__ short bhi_s(float x) {
    union { float f; unsigned u; } c; c.f = x; return (short)(c.u >> 16);
}
__device__ __forceinline__ float fhi_f(float x) {
    union { float f; unsigned u; } c; c.f = x; c.u &= 0xFFFF0000u; return c.f;
}
__device__ __forceinline__ short blo_s(float x) {
    return bhi_s(x - fhi_f(x));
}
// pack bf16(hi of a) into low16, bf16(hi of b) into high16
__device__ __forceinline__ unsigned pack_hi2(float a, float b) {
    union { float f; unsigned u; } x, y; x.f = a; y.f = b;
    return (x.u >> 16) | (y.u & 0xFFFF0000u);
}
// sigma(a) * tanh(b) with 2 exp + 1 rcp
__device__ __forceinline__ float sigtanh(float a, float b) {
    float ea = __expf(-a);
    float eb = __expf(-2.0f * b);
    return __fdividef(1.0f - eb, (1.0f + ea) * (1.0f + eb));
}
__device__ __forceinline__ float sigm_f(float x) {
    return __fdividef(1.0f, 1.0f + __expf(-x));
}

// ---------------- Stage 1: mean + segment embedding (transposed out) --------
extern "C" __global__ __launch_bounds__(384)
void k_seg(const float* __restrict__ x, const float* __restrict__ seg,
           float* __restrict__ seg_inT, float* __restrict__ meanw) {
    const int b = blockIdx.x;
    const int c = threadIdx.x;
    if (c >= NC) return;
    float sw[NW];
#pragma unroll
    for (int w = 0; w < NW; ++w) sw[w] = seg[c * NW + w];
    float acc[NS];
    float sum = 0.0f;
    const float* xb = x + (size_t)b * NL * NC + c;
#pragma unroll 1
    for (int s = 0; s < NS; ++s) {
        float a = 0.0f;
#pragma unroll
        for (int w = 0; w < NW; ++w) {
            float v = xb[(s * NW + w) * NC];
            sum += v;
            a = fmaf(v, sw[w], a);
        }
        acc[s] = a;
    }
    const float mean = sum * (1.0f / (float)NL);
    float ssum = 0.0f;
#pragma unroll
    for (int w = 0; w < NW; ++w) ssum += sw[w];
    meanw[b * NC + c] = mean;
#pragma unroll
    for (int s = 0; s < NS; ++s)
        seg_inT[((size_t)s * NC + c) * NB + b] = acc[s] - mean * ssum;
}

// ---------------- Stage 2: MFMA LSTM ----------------------------------------
// 4 independent waves/block, each owns (channel, 32-batch slab). No barriers.
// h kept in LDS as f32; bf16 hi/lo B-fragments rebuilt on read. K-slots:
// [0..24]=h, [25]=xt, [26]=1.0 (bias), [27]=0. gates via 3 chained MFMAs:
// Whi*hi, Wlo*hi, Whi*lo. Gate rows permuted so each lane's 4 C-regs are
// (i,f,g,o) of one hidden unit j = q*7+mg.
extern "C" __global__ __launch_bounds__(256, 4)
void k_lstm(const float* __restrict__ seg_inT, const float* __restrict__ W_ih,
            const float* __restrict__ W_hh, const float* __restrict__ b_ih,
            const float* __restrict__ b_hh, const float* __restrict__ Wp,
            const float* __restrict__ bp, float* __restrict__ preds) {
    const int c = blockIdx.x;
    const int wv = threadIdx.x >> 6;
    const int lane = threadIdx.x & 63;
    const int b0 = (blockIdx.y * WPB + wv) * BSL;
    const int bb = lane & 15;         // batch within 16-tile (B col)
    const int q  = lane >> 4;         // k-chunk / output row-quad

    __shared__ __align__(16) float hbuf[WPB][BSL * RSTF];
    float* __restrict__ hf = hbuf[wv];

    // ---- init h buffer (wave-private -> ordering via lgkmcnt, no barrier) ----
    for (int i = lane; i < BSL * RSTF; i += 64) hf[i] = 0.0f;
    if (lane < BSL) {
        hf[lane * RSTF + 26] = 1.0f;
        hf[lane * RSTF + 25] = seg_inT[(size_t)c * NB + b0 + lane];  // s=0
    }

    // ---- build hoisted A-fragments straight from global (one-time, L2) ----
    // A lane l: row=(l&15) <-> (gate=row&3, j=(row>>2)*7+mg), k=(l>>4)*8+e
    const int qq = bb >> 2, rr = bb & 3;
    const float* __restrict__ whh = W_hh + (size_t)c * NG * NH;
    const float* __restrict__ wxp = W_ih + (size_t)c * NG;
    const float* __restrict__ bip = b_ih + (size_t)c * NG;
    const float* __restrict__ bhp = b_hh + (size_t)c * NG;
    bf16x8 afr0[7], afr1[7];
#pragma unroll 1
    for (int mg = 0; mg < 7; ++mg) {
        const int jj = qq * 7 + mg;
        const int grow = rr * NH + jj;
        B8 f0, f1;
#pragma unroll
        for (int e = 0; e < 8; ++e) {
            const int k = q * 8 + e;
            short v0 = 0, v1 = 0;
            if (jj < NH) {
                if (k < NH) {
                    const float w = whh[grow * NH + k];
                    v0 = bhi_s(w); v1 = blo_s(w);
                } else if (k == 25) { v0 = bhi_s(wxp[grow]); v1 = blo_s(wxp[grow]); }
                else if (k == 26)   { const float bsum = bip[grow] + bhp[grow];
                                      v0 = bhi_s(bsum); v1 = blo_s(bsum); }
            }
            f0.s[e] = v0; f1.s[e] = v1;
        }
        afr0[mg] = f0.v; afr1[mg] = f1.v;
    }

    float wpl[7];
#pragma unroll
    for (int mg = 0; mg < 7; ++mg) {
        const int j = q * 7 + mg;
        wpl[mg] = (j < NH) ? Wp[(size_t)c * NH + j] : 0.0f;
    }
    const float bpc = bp[c];

    float cst[NBT][7];
#pragma unroll
    for (int nb = 0; nb < NBT; ++nb)
#pragma unroll
        for (int mg = 0; mg < 7; ++mg) cst[nb][mg] = 0.0f;

    // ---- recurrence ----
#pragma unroll 1
    for (int t = 0; t < NT; ++t) {
        const bool have_next = (t + 1 < NT);
        const bool enc_next = (t + 1 < NS);
        const bool do_proj = (t >= NS - 1);

        // prefetch next encoder input (global, L2-resident) a full step early
        float xnext = 0.0f;
        if (enc_next && q < 2)
            xnext = seg_inT[((size_t)(t + 1) * NC + c) * NB + b0 + q * 16 + bb];

        // read h rows (f32) and build hi/lo bf16 fragments
        bf16x8 bh[NBT], bl[NBT];
#pragma unroll
        for (int nb = 0; nb < NBT; ++nb) {
            const int b = nb * 16 + bb;
            const f32x4 r0 = *(const f32x4*)&hf[b * RSTF + q * 8];
            const f32x4 r1 = *(const f32x4*)&hf[b * RSTF + q * 8 + 4];
            BU ph, pl;
            ph.u[0] = pack_hi2(r0[0], r0[1]);
            ph.u[1] = pack_hi2(r0[2], r0[3]);
            ph.u[2] = pack_hi2(r1[0], r1[1]);
            ph.u[3] = pack_hi2(r1[2], r1[3]);
            const float d0 = r0[0] - fhi_f(r0[0]);
            const float d1 = r0[1] - fhi_f(r0[1]);
            const float d2 = r0[2] - fhi_f(r0[2]);
            const float d3 = r0[3] - fhi_f(r0[3]);
            const float d4 = r1[0] - fhi_f(r1[0]);
            const float d5 = r1[1] - fhi_f(r1[1]);
            const float d6 = r1[2] - fhi_f(r1[2]);
            const float d7 = r1[3] - fhi_f(r1[3]);
            pl.u[0] = pack_hi2(d0, d1);
            pl.u[1] = pack_hi2(d2, d3);
            pl.u[2] = pack_hi2(d4, d5);
            pl.u[3] = pack_hi2(d6, d7);
            bh[nb] = ph.v; bl[nb] = pl.v;
        }

#pragma unroll
        for (int nb = 0; nb < NBT; ++nb) {
            const int b = nb * 16 + bb;
            float pp = 0.0f;
#pragma unroll
            for (int mg = 0; mg < 7; ++mg) {
                f32x4 acc = {0.0f, 0.0f, 0.0f, 0.0f};
                acc = __builtin_amdgcn_mfma_f32_16x16x32_bf16(afr0[mg], bh[nb], acc, 0, 0, 0);
                acc = __builtin_amdgcn_mfma_f32_16x16x32_bf16(afr1[mg], bh[nb], acc, 0, 0, 0);
                acc = __builtin_amdgcn_mfma_f32_16x16x32_bf16(afr0[mg], bl[nb], acc, 0, 0, 0);
                // regs: 0=i, 1=f, 2=g, 3=o for hidden j=q*7+mg, batch b
                const float cn = fmaf(sigm_f(acc[1]), cst[nb][mg], sigtanh(acc[0], acc[2]));
                const float hn = sigtanh(acc[3], cn);
                cst[nb][mg] = cn;
                if (do_proj) pp = fmaf(hn, wpl[mg], pp);
                const int j = q * 7 + mg;
                if (j < NH) hf[b * RSTF + j] = hn;
            }
            if (do_proj) {
                pp += __shfl_xor(pp, 16);
                pp += __shfl_xor(pp, 32);
                const float ov = pp + bpc;
                if (q == 0) {
                    preds[((size_t)c * NP + (t - (NS - 1))) * NB + b0 + b] = ov;
                    if (have_next && !enc_next) hf[b * RSTF + 25] = ov;  // decoder input
                }
            }
        }
        if (enc_next && q < 2) hf[(q * 16 + bb) * RSTF + 25] = xnext;
    }
}

// ---------------- Stage 3: expand predictions to output ---------------------
extern "C" __global__ __launch_bounds__(384)
void k_out(const float* __restrict__ preds, const float* __restrict__ seg,
           const float* __restrict__ meanw, float* __restrict__ out) {
    const int b = blockIdx.x;
    const int c = threadIdx.x;
    if (c >= NC) return;
    float sw[NW];
#pragma unroll
    for (int w = 0; w < NW; ++w) sw[w] = seg[c * NW + w];
    const float mean = meanw[b * NC + c];
    float pv[NP];
#pragma unroll
    for (int p = 0; p < NP; ++p) pv[p] = preds[((size_t)c * NP + p) * NB + b];
    float* ob = out + (size_t)b * (NP * NW) * NC + c;
#pragma unroll
    for (int p = 0; p < NP; ++p) {
#pragma unroll
        for (int w = 0; w < NW; ++w) {
            ob[(p * NW + w) * NC] = fmaf(pv[p], sw[w], mean);
        }
    }
}

extern "C" void kernel_launch(void* const* d_in, const int* in_sizes, int n_in,
                              void* d_out, int out_size, void* d_ws, size_t ws_size,
                              hipStream_t stream) {
    const float* x    = (const float*)d_in[0];
    const float* seg  = (const float*)d_in[1];
    const float* W_ih = (const float*)d_in[2];
    const float* W_hh = (const float*)d_in[3];
    const float* b_ih = (const float*)d_in[4];
    const float* b_hh = (const float*)d_in[5];
    const float* Wp   = (const float*)d_in[6];
    const float* bp   = (const float*)d_in[7];
    float* out = (float*)d_out;

    float* seg_inT = (float*)d_ws;                     // 28*321*512
    float* meanw   = seg_inT + (size_t)NS * NC * NB;   // 512*321
    float* preds   = meanw + (size_t)NB * NC;          // 321*8*512

    k_seg<<<NB, 384, 0, stream>>>(x, seg, seg_inT, meanw);
    k_lstm<<<dim3(NC, NB / (BSL * WPB)), 256, 0, stream>>>(seg_inT, W_ih, W_hh, b_ih, b_hh, Wp, bp, preds);
    k_out<<<NB, 384, 0, stream>>>(preds, seg, meanw, out);
}

// Round 6
// 474.130 us; speedup vs baseline: 3.7018x; 1.1324x over previous
//
#include <hip/hip_runtime.h>
#include <math.h>

#define NB 512
#define NL 336
#define NC 321
#define NS 28
#define NW 12
#define NH 25
#define NP 8
#define NG 100
#define NT (NS + NP - 1)  // 35 cell steps
#define BSL 16            // batch slab per wave
#define RSTF 36           // h-row stride in f32 slots (=> ~4-way worst on b128)
#define WPB 4             // waves per block

typedef __attribute__((ext_vector_type(8))) short bf16x8;
typedef __attribute__((ext_vector_type(4))) float f32x4;

union B8 { bf16x8 v; short s[8]; };
union BU { bf16x8 v; unsigned u[4]; };

// round-to-nearest bf16 (for weights, built once)
__device__ __forceinline__ short brtn_s(float x) {
    union { float f; unsigned u; } c; c.f = x;
    return (short)((c.u + 0x8000u) >> 16);
}
__device__ __forceinline__ float fhi_f(float x) {
    union { float f; unsigned u; } c; c.f = x; c.u &= 0xFFFF0000u; return c.f;
}
// truncating split halves (for h/xt: hi + lo reconstruct exactly)
__device__ __forceinline__ short bhi_s(float x) {
    union { float f; unsigned u; } c; c.f = x; return (short)(c.u >> 16);
}
// pack bf16(hi of a) low16 | bf16(hi of b) high16
__device__ __forceinline__ unsigned pack_hi2(float a, float b) {
    union { float f; unsigned u; } x, y; x.f = a; y.f = b;
    return (x.u >> 16) | (y.u & 0xFFFF0000u);
}
// sigma(a) * tanh(b): 2 exp + 1 rcp
__device__ __forceinline__ float sigtanh(float a, float b) {
    float ea = __expf(-a);
    float eb = __expf(-2.0f * b);
    return __fdividef(1.0f - eb, (1.0f + ea) * (1.0f + eb));
}
__device__ __forceinline__ float sigm_f(float x) {
    return __fdividef(1.0f, 1.0f + __expf(-x));
}

// ---------------- Stage 1: mean + segment embedding (transposed out) --------
extern "C" __global__ __launch_bounds__(384)
void k_seg(const float* __restrict__ x, const float* __restrict__ seg,
           float* __restrict__ seg_inT, float* __restrict__ meanw) {
    const int b = blockIdx.x;
    const int c = threadIdx.x;
    if (c >= NC) return;
    float sw[NW];
#pragma unroll
    for (int w = 0; w < NW; ++w) sw[w] = seg[c * NW + w];
    float acc[NS];
    float sum = 0.0f;
    const float* xb = x + (size_t)b * NL * NC + c;
#pragma unroll 1
    for (int s = 0; s < NS; ++s) {
        float a = 0.0f;
#pragma unroll
        for (int w = 0; w < NW; ++w) {
            float v = xb[(s * NW + w) * NC];
            sum += v;
            a = fmaf(v, sw[w], a);
        }
        acc[s] = a;
    }
    const float mean = sum * (1.0f / (float)NL);
    float ssum = 0.0f;
#pragma unroll
    for (int w = 0; w < NW; ++w) ssum += sw[w];
    meanw[b * NC + c] = mean;
#pragma unroll
    for (int s = 0; s < NS; ++s)
        seg_inT[((size_t)s * NC + c) * NB + b] = acc[s] - mean * ssum;
}

// ---------------- Stage 2: MFMA LSTM ----------------------------------------
// One wave per (channel, 16-batch tile); 4 waves/block, no barriers.
// W single bf16 (RTN); h/xt split hi/lo -> 2 chained MFMAs per gate-tile.
// K-slots: [0..24]=h, [25]=xt (A=wx_hi), [26]=1@hi (A=bias_hi),
// [27]=1@lo (A=bias_lo), [28]=xt_hi@hi (A=wx_lo). Gate rows permuted so each
// lane's 4 C-regs are (i,f,g,o) of hidden j = q*7+mg, batch bb.
extern "C" __global__ __launch_bounds__(256, 4)
void k_lstm(const float* __restrict__ seg_inT, const float* __restrict__ W_ih,
            const float* __restrict__ W_hh, const float* __restrict__ b_ih,
            const float* __restrict__ b_hh, const float* __restrict__ Wp,
            const float* __restrict__ bp, float* __restrict__ preds) {
    const int c = blockIdx.x;
    const int wv = threadIdx.x >> 6;
    const int lane = threadIdx.x & 63;
    const int b0 = (blockIdx.y * WPB + wv) * BSL;
    const int bb = lane & 15;         // batch col / A gate-row
    const int q  = lane >> 4;         // k-chunk / C row-quad

    __shared__ __align__(16) float hbuf[WPB][BSL * RSTF];
    float* __restrict__ hf = hbuf[wv];

    // ---- init h buffer (wave-private; ordering via compiler lgkmcnt) ----
    for (int i = lane; i < BSL * RSTF; i += 64) hf[i] = 0.0f;
    if (lane < BSL)
        hf[lane * RSTF + 25] = seg_inT[(size_t)c * NB + b0 + lane];  // s=0

    // ---- hoisted A-fragments from global (one-time, L2-resident) ----
    // A lane: gate-row = bb <-> (gate=bb&3, j=(bb>>2)*7+mg), k=(q)*8+e
    const int qq = bb >> 2, rr = bb & 3;
    const float* __restrict__ whh = W_hh + (size_t)c * NG * NH;
    const float* __restrict__ wxp = W_ih + (size_t)c * NG;
    const float* __restrict__ bip = b_ih + (size_t)c * NG;
    const float* __restrict__ bhp = b_hh + (size_t)c * NG;
    bf16x8 afr[7];
#pragma unroll 1
    for (int mg = 0; mg < 7; ++mg) {
        const int jj = qq * 7 + mg;
        const int grow = rr * NH + jj;
        B8 f0;
#pragma unroll
        for (int e = 0; e < 8; ++e) {
            const int k = q * 8 + e;
            short v0 = 0;
            if (jj < NH) {
                if (k < NH)         v0 = brtn_s(whh[grow * NH + k]);
                else if (k == 25)   v0 = brtn_s(wxp[grow]);
                else if (k == 26)   v0 = bhi_s(bip[grow] + bhp[grow]);
                else if (k == 27)   { const float bs = bip[grow] + bhp[grow];
                                      v0 = brtn_s(bs - fhi_f(bs)); }
                else if (k == 28)   { const float wx = wxp[grow];
                                      v0 = brtn_s(wx - fhi_f(wx)); }
            }
            f0.s[e] = v0;
        }
        afr[mg] = f0.v;
    }

    float wpl[7];
#pragma unroll
    for (int mg = 0; mg < 7; ++mg) {
        const int j = q * 7 + mg;
        wpl[mg] = (j < NH) ? Wp[(size_t)c * NH + j] : 0.0f;
    }
    const float bpc = bp[c];
    const bool q3 = (q == 3);

    float cst[7];
#pragma unroll
    for (int mg = 0; mg < 7; ++mg) cst[mg] = 0.0f;

    // ---- recurrence ----
#pragma unroll 1
    for (int t = 0; t < NT; ++t) {
        const bool have_next = (t + 1 < NT);
        const bool enc_next = (t + 1 < NS);
        const bool do_proj = (t >= NS - 1);

        // prefetch next encoder input (L2/L3-resident) a full step early
        float xnext = 0.0f;
        if (enc_next && q == 0)
            xnext = seg_inT[((size_t)(t + 1) * NC + c) * NB + b0 + bb];

        // read h row (f32) and build hi/lo bf16 fragments
        const f32x4 r0 = *(const f32x4*)&hf[bb * RSTF + q * 8];
        const f32x4 r1 = *(const f32x4*)&hf[bb * RSTF + q * 8 + 4];
        BU ph, pl;
        ph.u[0] = pack_hi2(r0[0], r0[1]);
        ph.u[1] = pack_hi2(r0[2], r0[3]);
        ph.u[2] = pack_hi2(r1[0], r1[1]);
        ph.u[3] = pack_hi2(r1[2], r1[3]);
        const float d0 = r0[0] - fhi_f(r0[0]);
        const float d1 = r0[1] - fhi_f(r0[1]);
        const float d2 = r0[2] - fhi_f(r0[2]);
        const float d3 = r0[3] - fhi_f(r0[3]);
        const float d4 = r1[0] - fhi_f(r1[0]);
        const float d5 = r1[1] - fhi_f(r1[1]);
        const float d6 = r1[2] - fhi_f(r1[2]);
        const float d7 = r1[3] - fhi_f(r1[3]);
        pl.u[0] = pack_hi2(d0, d1);
        pl.u[1] = pack_hi2(d2, d3);
        pl.u[2] = pack_hi2(d4, d5);
        pl.u[3] = pack_hi2(d6, d7);
        // q==3 slot overrides: k26 -> bh=1 (bias_hi), k27 -> bl=1 (bias_lo),
        // k28 -> bh=xt_hi (wx_lo term). r0[1] = hf[25] = xt for q==3.
        {
            union { float f; unsigned u; } xu; xu.f = r0[1];
            ph.u[1] = q3 ? 0x00003F80u : ph.u[1];
            pl.u[1] = q3 ? 0x3F800000u : pl.u[1];
            ph.u[2] = q3 ? (xu.u >> 16) : ph.u[2];
            pl.u[2] = q3 ? 0u : pl.u[2];
        }

        float pp = 0.0f;
#pragma unroll
        for (int mg = 0; mg < 7; ++mg) {
            f32x4 acc = {0.0f, 0.0f, 0.0f, 0.0f};
            acc = __builtin_amdgcn_mfma_f32_16x16x32_bf16(afr[mg], ph.v, acc, 0, 0, 0);
            acc = __builtin_amdgcn_mfma_f32_16x16x32_bf16(afr[mg], pl.v, acc, 0, 0, 0);
            // regs: 0=i, 1=f, 2=g, 3=o for hidden j=q*7+mg, batch bb
            const float cn = fmaf(sigm_f(acc[1]), cst[mg], sigtanh(acc[0], acc[2]));
            const float hn = sigtanh(acc[3], cn);
            cst[mg] = cn;
            if (do_proj) pp = fmaf(hn, wpl[mg], pp);
            const int j = q * 7 + mg;
            if (j < NH) hf[bb * RSTF + j] = hn;
        }

        if (do_proj) {
            pp += __shfl_xor(pp, 16);
            pp += __shfl_xor(pp, 32);
            const float ov = pp + bpc;
            if (q == 0) {
                preds[((size_t)c * NP + (t - (NS - 1))) * NB + b0 + bb] = ov;
                if (have_next && !enc_next) hf[bb * RSTF + 25] = ov;  // decoder in
            }
        }
        if (enc_next && q == 0) hf[bb * RSTF + 25] = xnext;
    }
}

// ---------------- Stage 3: expand predictions to output ---------------------
extern "C" __global__ __launch_bounds__(384)
void k_out(const float* __restrict__ preds, const float* __restrict__ seg,
           const float* __restrict__ meanw, float* __restrict__ out) {
    const int b = blockIdx.x;
    const int c = threadIdx.x;
    if (c >= NC) return;
    float sw[NW];
#pragma unroll
    for (int w = 0; w < NW; ++w) sw[w] = seg[c * NW + w];
    const float mean = meanw[b * NC + c];
    float pv[NP];
#pragma unroll
    for (int p = 0; p < NP; ++p) pv[p] = preds[((size_t)c * NP + p) * NB + b];
    float* ob = out + (size_t)b * (NP * NW) * NC + c;
#pragma unroll
    for (int p = 0; p < NP; ++p) {
#pragma unroll
        for (int w = 0; w < NW; ++w) {
            ob[(p * NW + w) * NC] = fmaf(pv[p], sw[w], mean);
        }
    }
}

extern "C" void kernel_launch(void* const* d_in, const int* in_sizes, int n_in,
                              void* d_out, int out_size, void* d_ws, size_t ws_size,
                              hipStream_t stream) {
    const float* x    = (const float*)d_in[0];
    const float* seg  = (const float*)d_in[1];
    const float* W_ih = (const float*)d_in[2];
    const float* W_hh = (const float*)d_in[3];
    const float* b_ih = (const float*)d_in[4];
    const float* b_hh = (const float*)d_in[5];
    const float* Wp   = (const float*)d_in[6];
    const float* bp   = (const float*)d_in[7];
    float* out = (float*)d_out;

    float* seg_inT = (float*)d_ws;                     // 28*321*512
    float* meanw   = seg_inT + (size_t)NS * NC * NB;   // 512*321
    float* preds   = meanw + (size_t)NB * NC;          // 321*8*512

    k_seg<<<NB, 384, 0, stream>>>(x, seg, seg_inT, meanw);
    k_lstm<<<dim3(NC, NB / (BSL * WPB)), 256, 0, stream>>>(seg_inT, W_ih, W_hh, b_ih, b_hh, Wp, bp, preds);
    k_out<<<NB, 384, 0, stream>>>(preds, seg, meanw, out);
}